// Round 10
// baseline (180.847 us; speedup 1.0000x reference)
//
#include <hip/hip_runtime.h>
#include <hip/hip_bf16.h>
#include <hip/hip_cooperative_groups.h>

#define HIDDEN 2048
#define NT 16            // K tiles of 128 (fp4: 64 B per row per tile)
#define LDS_BYTES 65536  // 2 bufs x (A 16KB + B 16KB)

typedef __attribute__((ext_vector_type(4))) float f32x4;
typedef __attribute__((ext_vector_type(4))) int   i32x4;
typedef __attribute__((ext_vector_type(8))) int   i32x8;

#define GLDS(gptr, lptr)                                                       \
    __builtin_amdgcn_global_load_lds(                                          \
        (const __attribute__((address_space(1))) void*)(gptr),                 \
        (__attribute__((address_space(3))) void*)(lptr), 16, 0, 0)

#define SCHED0() __builtin_amdgcn_sched_barrier(0)
#define BARRIER() __builtin_amdgcn_s_barrier()
#define LGKMC(n) do { asm volatile("s_waitcnt lgkmcnt(" #n ")" ::: "memory"); SCHED0(); } while (0)
#define VMCNT(n)  do { asm volatile("s_waitcnt vmcnt(" #n ")" ::: "memory"); SCHED0(); } while (0)
#define PRIO1() __builtin_amdgcn_s_setprio(1)
#define PRIO0() __builtin_amdgcn_s_setprio(0)

#define SCALE1 0x7F7F7F7F   // E8M0 = 1.0 in every byte

// FMT code 4 = fp4 (e2m1) for both A (cbsz) and B (blgp)
#define MFMA4(a, b, c)                                                         \
    __builtin_amdgcn_mfma_scale_f32_16x16x128_f8f6f4(                          \
        (a), (b), (c), 4, 4, 0, SCALE1, 0, SCALE1)

// ---- e2m1 quantize (RNE by midpoint thresholds) ----
__device__ __forceinline__ unsigned q_e2m1(float x) {
    float v = fabsf(x);
    unsigned n;
    if      (v < 0.25f) n = 0;
    else if (v < 0.75f) n = 1;   // 0.5
    else if (v < 1.25f) n = 2;   // 1.0
    else if (v < 1.75f) n = 3;   // 1.5
    else if (v < 2.5f)  n = 4;   // 2
    else if (v < 3.5f)  n = 5;   // 3
    else if (v < 5.0f)  n = 6;   // 4
    else                n = 7;   // 6
    return n | (x < 0.0f ? 8u : 0u);
}

__device__ __forceinline__ unsigned pack8_e2m1(const f32x4& a, const f32x4& b,
                                               float scale) {
    unsigned w = 0;
    #pragma unroll
    for (int k = 0; k < 4; ++k) {
        w |= q_e2m1(a[k] * scale) << (4 * k);
        w |= q_e2m1(b[k] * scale) << (16 + 4 * k);
    }
    return w;
}

// ================= ONE cooperative kernel: prep + scatter + convw + GEMM ======
__global__ __launch_bounds__(512, 2) void mega_kernel(
    const float* __restrict__ xc,
    const float* __restrict__ xp,
    const float* __restrict__ alpha_p,
    const float* __restrict__ vals,
    const int*   __restrict__ rows,
    const int*   __restrict__ cols,
    float* __restrict__ out,
    float* __restrict__ W,                   // ws: f32 [2048][2048]
    unsigned char* __restrict__ w4,          // ws: fp4 [2048][1024 B], x1024
    unsigned char* __restrict__ xp4,         // ws: fp4 [8192][1024 B]
    int nnz, int n8xp)
{
    extern __shared__ __align__(16) char lds[];
    cooperative_groups::grid_group grid = cooperative_groups::this_grid();

    const int gtid    = blockIdx.x * blockDim.x + threadIdx.x;
    const int gstride = gridDim.x * blockDim.x;   // 131072

    // ---- Phase A: zero W (f32) + convert xp -> fp4 ----
    for (int j = gtid; j < (HIDDEN * HIDDEN / 4); j += gstride)
        ((f32x4*)W)[j] = (f32x4){0.f, 0.f, 0.f, 0.f};
    for (int j = gtid; j < n8xp; j += gstride) {
        f32x4 a = ((const f32x4*)xp)[2 * j];
        f32x4 b = ((const f32x4*)xp)[2 * j + 1];
        ((unsigned int*)xp4)[j] = pack8_e2m1(a, b, 1.0f);
    }
    grid.sync();

    // ---- Phase B: COO scatter with duplicate summing ----
    for (int k = gtid; k < nnz; k += gstride)
        atomicAdd(&W[(size_t)rows[k] * HIDDEN + cols[k]], vals[k]);
    grid.sync();

    // ---- Phase C: convert W (x1024) -> fp4 ----
    for (int j = gtid; j < (HIDDEN * HIDDEN / 8); j += gstride) {
        f32x4 a = ((const f32x4*)W)[2 * j];
        f32x4 b = ((const f32x4*)W)[2 * j + 1];
        ((unsigned int*)w4)[j] = pack8_e2m1(a, b, 1024.0f);
    }
    grid.sync();

    // ---- Phase D: 256x256xK128 8-wave MX-fp4 GEMM (r8 structure) ----
    const int tid  = threadIdx.x;
    const int lane = tid & 63;
    const int wave = tid >> 6;
    const int l15  = lane & 15;
    const int l4   = lane >> 4;

    // XCD-chunked bijective mapping
    const int xcd = blockIdx.x & 7;
    const int loc = blockIdx.x >> 3;          // 0..31
    const int m0  = (xcd * 4 + (loc >> 3)) * 256;
    const int n0  = (loc & 7) * 256;

    const int wm = (wave >> 2) * 128;   // 2 M-waves
    const int wn = (wave & 3) * 64;     // 4 N-waves

    // staging: tile 256 rows x 64 B (fp4); wave owns 32 rows = 2 gloads/matrix.
    const int srow = lane >> 2;               // 0..15
    const int sw   = (lane & 3) ^ ((srow >> 1) & 3);
    const unsigned char* const gA = xp4 + (size_t)(m0 + wave * 32 + srow) * 1024 + sw * 16;
    const unsigned char* const gB = w4  + (size_t)(n0 + wave * 32 + srow) * 1024 + sw * 16;

#define STAGE(t)                                                               \
    do {                                                                       \
        const int _t = (t);                                                    \
        if (_t < NT) {                                                         \
            const size_t _o = (size_t)_t * 64;                                 \
            char* const _dA = lds + (_t & 1) * 32768 + wave * 2048 + lane * 16;\
            char* const _dB = _dA + 16384;                                     \
            GLDS(gA + _o,          _dA);                                       \
            GLDS(gA + _o + 16384,  _dA + 1024);   /* +16 rows */               \
            GLDS(gB + _o,          _dB);                                       \
            GLDS(gB + _o + 16384,  _dB + 1024);                                \
        }                                                                      \
    } while (0)

    // ds_read: lane reads row (base + l15), k-chunk l4; stored chunk ^ swizzle
    const int kx   = (l4 ^ ((l15 >> 1) & 3)) * 16;
    const int rowb = l15 * 64;

#define LDFRAG(dst, base)                                                      \
    do {                                                                       \
        i32x4 _v = *(const i32x4*)((base) + rowb + kx);                        \
        (dst) = __builtin_shufflevector(_v, (i32x4){0, 0, 0, 0},               \
                                        0, 1, 2, 3, 4, 5, 6, 7);               \
    } while (0)

    f32x4 acc[8][4] = {};
    i32x8 a0[4], a1[4], b01[2], b23[2];

    STAGE(0);
    VMCNT(0);
    SCHED0(); BARRIER(); SCHED0();

    for (int tt = 0; tt < NT; ++tt) {
        const char* const Ab = lds + (tt & 1) * 32768 + wm * 64;
        const char* const Bb = lds + (tt & 1) * 32768 + 16384 + wn * 64;

        STAGE(tt + 1);
        SCHED0();

        #pragma unroll
        for (int mi = 0; mi < 4; ++mi)
            LDFRAG(a0[mi], Ab + mi * 1024);
        SCHED0();

        if (tt) {   // deferred Q4 of previous tile
            PRIO1();
            #pragma unroll
            for (int mi = 0; mi < 4; ++mi)
                #pragma unroll
                for (int nj = 0; nj < 2; ++nj)
                    acc[4 + mi][nj] = MFMA4(a1[mi], b01[nj], acc[4 + mi][nj]);
            PRIO0();
        }
        SCHED0();

        #pragma unroll
        for (int nj = 0; nj < 2; ++nj)
            LDFRAG(b01[nj], Bb + nj * 1024);
        SCHED0();
        LGKMC(2);            // a0 done (b01 flying)

        #pragma unroll
        for (int nj = 0; nj < 2; ++nj)
            LDFRAG(b23[nj], Bb + (2 + nj) * 1024);
        SCHED0();
        LGKMC(2);            // b01 done (b23 flying)

        PRIO1();             // Q1: a0 x b01
        #pragma unroll
        for (int mi = 0; mi < 4; ++mi)
            #pragma unroll
            for (int nj = 0; nj < 2; ++nj)
                acc[mi][nj] = MFMA4(a0[mi], b01[nj], acc[mi][nj]);
        PRIO0();
        SCHED0();

        #pragma unroll
        for (int mi = 0; mi < 4; ++mi)
            LDFRAG(a1[mi], Ab + (4 + mi) * 1024);
        SCHED0();
        LGKMC(4);            // b23 done (a1 flying)

        PRIO1();             // Q2: a0 x b23
        #pragma unroll
        for (int mi = 0; mi < 4; ++mi)
            #pragma unroll
            for (int nj = 0; nj < 2; ++nj)
                acc[mi][2 + nj] = MFMA4(a0[mi], b23[nj], acc[mi][2 + nj]);
        PRIO0();
        SCHED0();
        LGKMC(0);            // a1 done

        PRIO1();             // Q3: a1 x b23
        #pragma unroll
        for (int mi = 0; mi < 4; ++mi)
            #pragma unroll
            for (int nj = 0; nj < 2; ++nj)
                acc[4 + mi][2 + nj] = MFMA4(a1[mi], b23[nj], acc[4 + mi][2 + nj]);
        PRIO0();
        SCHED0();

        VMCNT(0);            // tile t+1 landed (drains whatever is outstanding)
        BARRIER(); SCHED0();
    }

    // final deferred Q4
    PRIO1();
    #pragma unroll
    for (int mi = 0; mi < 4; ++mi)
        #pragma unroll
        for (int nj = 0; nj < 2; ++nj)
            acc[4 + mi][nj] = MFMA4(a1[mi], b01[nj], acc[4 + mi][nj]);
    PRIO0();

    // ---- epilogue: out = xc + (alpha/1024) * acc ----
    const float alpha = alpha_p[0] * (1.0f / 1024.0f);
    #pragma unroll
    for (int mi = 0; mi < 8; ++mi) {
        #pragma unroll
        for (int r = 0; r < 4; ++r) {
            const int m = m0 + wm + mi * 16 + l4 * 4 + r;
            #pragma unroll
            for (int nj = 0; nj < 4; ++nj) {
                const int n = n0 + wn + nj * 16 + l15;
                const size_t o = (size_t)m * HIDDEN + n;
                out[o] = xc[o] + alpha * acc[mi][nj][r];
            }
        }
    }
#undef STAGE
#undef LDFRAG
}

extern "C" void kernel_launch(void* const* d_in, const int* in_sizes, int n_in,
                              void* d_out, int out_size, void* d_ws, size_t ws_size,
                              hipStream_t stream) {
    const float* xc    = (const float*)d_in[0];
    const float* xp    = (const float*)d_in[1];
    const float* alpha = (const float*)d_in[2];
    const float* vals  = (const float*)d_in[3];
    const int*   idx   = (const int*)d_in[4];
    float* out = (float*)d_out;

    float*         W   = (float*)d_ws;                                  // 16 MB
    unsigned char* W4  = (unsigned char*)((char*)d_ws + (16 << 20));    //  2 MB
    unsigned char* xp4 = (unsigned char*)((char*)d_ws + (18 << 20));    // 8.4 MB

    int nnz  = in_sizes[3];
    int n8xp = in_sizes[1] / 8;
    const int M = in_sizes[0] / HIDDEN;     // 8192

    (void)hipFuncSetAttribute((const void*)mega_kernel,
                              hipFuncAttributeMaxDynamicSharedMemorySize, LDS_BYTES);

    const int* rows = idx;
    const int* cols = idx + nnz;

    void* args[] = {
        (void*)&xc, (void*)&xp, (void*)&alpha, (void*)&vals,
        (void*)&rows, (void*)&cols, (void*)&out,
        (void*)&W, (void*)&W4, (void*)&xp4, (void*)&nnz, (void*)&n8xp
    };

    dim3 grid((M / 256) * 8);   // 256 blocks = 1/CU (co-resident)
    dim3 block(512);
    (void)hipLaunchCooperativeKernel((const void*)mega_kernel, grid, block,
                                     args, LDS_BYTES, stream);
}

// Round 11
// 83.753 us; speedup vs baseline: 2.1593x; 2.1593x over previous
//
#include <hip/hip_runtime.h>
#include <hip/hip_bf16.h>

#define HIDDEN 2048
#define NT 16            // K tiles of 128 (fp4: 64 B per row per tile)
#define LDS_BYTES 49152  // 2 bufs x (A 16KB + B 8KB)

typedef __attribute__((ext_vector_type(4))) float f32x4;
typedef __attribute__((ext_vector_type(4))) int   i32x4;
typedef __attribute__((ext_vector_type(8))) int   i32x8;

#define GLDS(gptr, lptr)                                                       \
    __builtin_amdgcn_global_load_lds(                                          \
        (const __attribute__((address_space(1))) void*)(gptr),                 \
        (__attribute__((address_space(3))) void*)(lptr), 16, 0, 0)

#define SCHED0() __builtin_amdgcn_sched_barrier(0)
#define BARRIER() __builtin_amdgcn_s_barrier()
#define LGKMC(n) do { asm volatile("s_waitcnt lgkmcnt(" #n ")" ::: "memory"); SCHED0(); } while (0)
#define VMCNT(n)  do { asm volatile("s_waitcnt vmcnt(" #n ")" ::: "memory"); SCHED0(); } while (0)
#define PRIO1() __builtin_amdgcn_s_setprio(1)
#define PRIO0() __builtin_amdgcn_s_setprio(0)

#define SCALE1 0x7F7F7F7F   // E8M0 = 1.0 in every byte

// FMT code 4 = fp4 (e2m1) for both A (cbsz) and B (blgp)
#define MFMA4(a, b, c)                                                         \
    __builtin_amdgcn_mfma_scale_f32_16x16x128_f8f6f4(                          \
        (a), (b), (c), 4, 4, 0, SCALE1, 0, SCALE1)

// ---- Build dense W (f32) from COO with duplicate summing ----
__global__ void build_w_kernel(const float* __restrict__ vals,
                               const int* __restrict__ rows,
                               const int* __restrict__ cols,
                               float* __restrict__ W, int nnz) {
    int k = blockIdx.x * blockDim.x + threadIdx.x;
    if (k < nnz) atomicAdd(&W[(size_t)rows[k] * HIDDEN + cols[k]], vals[k]);
}

// ---- e2m1 quantize (RNE by midpoint thresholds) ----
__device__ __forceinline__ unsigned q_e2m1(float x) {
    float v = fabsf(x);
    unsigned n;
    if      (v < 0.25f) n = 0;
    else if (v < 0.75f) n = 1;   // 0.5
    else if (v < 1.25f) n = 2;   // 1.0
    else if (v < 1.75f) n = 3;   // 1.5
    else if (v < 2.5f)  n = 4;   // 2
    else if (v < 3.5f)  n = 5;   // 3
    else if (v < 5.0f)  n = 6;   // 4
    else                n = 7;   // 6
    return n | (x < 0.0f ? 8u : 0u);
}

// ---- fused f32 -> fp4 e2m1 packed: [xp | W*1024]; 8 elems -> 1 uint ----
__global__ void convert_kernel(const float* __restrict__ xp,
                               unsigned int* __restrict__ xp4, int n8xp,
                               const float* __restrict__ W,
                               unsigned int* __restrict__ W4, int n8w) {
    int i = blockIdx.x * blockDim.x + threadIdx.x;
    const int stride = gridDim.x * blockDim.x;
    const int total = n8xp + n8w;
    for (; i < total; i += stride) {
        const bool isxp = (i < n8xp);
        const float* src = isxp ? xp : W;
        unsigned int* dst = isxp ? xp4 : W4;
        const float scale = isxp ? 1.0f : 1024.0f;
        const int j = isxp ? i : i - n8xp;
        f32x4 a = ((const f32x4*)src)[2 * j];
        f32x4 b = ((const f32x4*)src)[2 * j + 1];
        unsigned int w = 0;
        #pragma unroll
        for (int k = 0; k < 4; ++k) {
            w |= q_e2m1(a[k] * scale) << (4 * k);
            w |= q_e2m1(b[k] * scale) << (16 + 4 * k);
        }
        dst[j] = w;
    }
}

// ---- 256x128xK128 8-wave MX-fp4 GEMM, 2 blocks/CU ----
__global__ __launch_bounds__(512, 4) void gemm_kernel(
    const float* __restrict__ xc,
    const unsigned char* __restrict__ xp4,   // fp4 [8192][1024 B]
    const unsigned char* __restrict__ w4,    // fp4 [2048][1024 B], values x1024
    const float* __restrict__ alpha_p,
    float* __restrict__ out)
{
    extern __shared__ __align__(16) char lds[];

    const int tid  = threadIdx.x;
    const int lane = tid & 63;
    const int wave = tid >> 6;
    const int l15  = lane & 15;
    const int l4   = lane >> 4;

    // XCD-chunked bijective mapping: 512 blocks = 8 XCD x (4 m-tiles x 16 n-tiles)
    // Per XCD: A slice 1MB + W4 2MB -> L2-resident.
    const int xcd = blockIdx.x & 7;
    const int loc = blockIdx.x >> 3;          // 0..63
    const int m0  = (xcd * 4 + (loc >> 4)) * 256;
    const int n0  = (loc & 15) * 128;

    const int wm = (wave >> 1) * 64;    // 4 M-waves
    const int wn = (wave & 1) * 64;     // 2 N-waves

    // ---- staging: A tile 256 rows x 64B (2 GLDS/thread), B tile 128 rows (1) ----
    // srow = lane>>2 (row%16 within group); chunk = lane&3, source-swizzled.
    const int srow = lane >> 2;               // 0..15
    const int sw   = (lane & 3) ^ ((srow >> 1) & 3);
    const unsigned char* const gA = xp4 + (size_t)(m0 + wave * 32 + srow) * 1024 + sw * 16;
    const unsigned char* const gB = w4  + (size_t)(n0 + wave * 16 + srow) * 1024 + sw * 16;

#define STAGE(t)                                                               \
    do {                                                                       \
        const int _t = (t);                                                    \
        if (_t < NT) {                                                         \
            const size_t _o = (size_t)_t * 64;                                 \
            char* const _dA = lds + (_t & 1) * 24576 + wave * 2048 + lane * 16;\
            char* const _dB = lds + (_t & 1) * 24576 + 16384 + wave * 1024 + lane * 16; \
            GLDS(gA + _o,          _dA);                                       \
            GLDS(gA + _o + 16384,  _dA + 1024);   /* rows +16 */               \
            GLDS(gB + _o,          _dB);                                       \
        }                                                                      \
    } while (0)

    // ---- ds_read: lane reads row (base + l15), k-chunk l4; stored chunk ^ swz ----
    const int kx   = (l4 ^ ((l15 >> 1) & 3)) * 16;
    const int rowb = l15 * 64;

#define LDFRAG(dst, base)                                                      \
    do {                                                                       \
        i32x4 _v = *(const i32x4*)((base) + rowb + kx);                        \
        (dst) = __builtin_shufflevector(_v, (i32x4){0, 0, 0, 0},               \
                                        0, 1, 2, 3, 4, 5, 6, 7);               \
    } while (0)

    f32x4 acc[4][4] = {};
    i32x8 a[4], b01[2], b23[2];

    // ---- prologue ----
    STAGE(0);
    VMCNT(0);
    SCHED0(); BARRIER(); SCHED0();

    for (int tt = 0; tt < NT; ++tt) {
        const char* const Ab = lds + (tt & 1) * 24576 + wm * 64;
        const char* const Bb = lds + (tt & 1) * 24576 + 16384 + wn * 64;

        STAGE(tt + 1);           // 3 vm loads; waited at the bottom VMCNT
        SCHED0();

        #pragma unroll
        for (int mi = 0; mi < 4; ++mi)
            LDFRAG(a[mi], Ab + mi * 1024);
        #pragma unroll
        for (int nj = 0; nj < 2; ++nj)
            LDFRAG(b01[nj], Bb + nj * 1024);
        SCHED0();
        LGKMC(2);                // a done (b01 flying)

        #pragma unroll
        for (int nj = 0; nj < 2; ++nj)
            LDFRAG(b23[nj], Bb + (2 + nj) * 1024);
        SCHED0();
        LGKMC(2);                // b01 done (b23 flying)

        PRIO1();                 // Q1: a x b01 (b23 completes underneath)
        #pragma unroll
        for (int mi = 0; mi < 4; ++mi)
            #pragma unroll
            for (int nj = 0; nj < 2; ++nj)
                acc[mi][nj] = MFMA4(a[mi], b01[nj], acc[mi][nj]);
        PRIO0();
        SCHED0();
        LGKMC(0);                // b23 done

        PRIO1();                 // Q2: a x b23
        #pragma unroll
        for (int mi = 0; mi < 4; ++mi)
            #pragma unroll
            for (int nj = 0; nj < 2; ++nj)
                acc[mi][2 + nj] = MFMA4(a[mi], b23[nj], acc[mi][2 + nj]);
        PRIO0();
        SCHED0();

        VMCNT(0);                // tile t+1 landed (issued a full body ago)
        BARRIER(); SCHED0();
    }

    // ---- epilogue: out = xc + (alpha/1024) * acc   (W pre-scaled x1024) ----
    const float alpha = alpha_p[0] * (1.0f / 1024.0f);
    #pragma unroll
    for (int mi = 0; mi < 4; ++mi) {
        #pragma unroll
        for (int r = 0; r < 4; ++r) {
            const int m = m0 + wm + mi * 16 + l4 * 4 + r;
            #pragma unroll
            for (int nj = 0; nj < 4; ++nj) {
                const int n = n0 + wn + nj * 16 + l15;
                const size_t o = (size_t)m * HIDDEN + n;
                out[o] = xc[o] + alpha * acc[mi][nj][r];
            }
        }
    }
#undef STAGE
#undef LDFRAG
}

extern "C" void kernel_launch(void* const* d_in, const int* in_sizes, int n_in,
                              void* d_out, int out_size, void* d_ws, size_t ws_size,
                              hipStream_t stream) {
    const float* xc    = (const float*)d_in[0];
    const float* xp    = (const float*)d_in[1];
    const float* alpha = (const float*)d_in[2];
    const float* vals  = (const float*)d_in[3];
    const int*   idx   = (const int*)d_in[4];
    float* out = (float*)d_out;

    float*         W   = (float*)d_ws;                                  // 16 MB
    unsigned char* W4  = (unsigned char*)((char*)d_ws + (16 << 20));    //  2 MB
    unsigned char* xp4 = (unsigned char*)((char*)d_ws + (18 << 20));    // 8.4 MB

    const int nnz = in_sizes[3];
    const int M   = in_sizes[0] / HIDDEN;   // 8192

    (void)hipFuncSetAttribute((const void*)gemm_kernel,
                              hipFuncAttributeMaxDynamicSharedMemorySize, LDS_BYTES);

    hipMemsetAsync(W, 0, (size_t)HIDDEN * HIDDEN * sizeof(float), stream);
    build_w_kernel<<<(nnz + 255) / 256, 256, 0, stream>>>(vals, idx, idx + nnz, W, nnz);

    convert_kernel<<<2048, 256, 0, stream>>>(xp, (unsigned int*)xp4, in_sizes[1] / 8,
                                             W, (unsigned int*)W4, (HIDDEN * HIDDEN) / 8);

    dim3 grid((M / 256) * 16);   // 32 m-tiles x 16 n-tiles = 512 blocks (2/CU)
    gemm_kernel<<<grid, 512, LDS_BYTES, stream>>>(xc, xp4, W4, alpha, out);
}

// Round 12
// 81.689 us; speedup vs baseline: 2.2138x; 1.0253x over previous
//
#include <hip/hip_runtime.h>
#include <hip/hip_bf16.h>

#define HIDDEN 2048
#define NT 16            // K tiles of 128 fp4 elems (64 B per row per tile)
#define LDS_BYTES 49152  // 2 bufs x (A 16KB + B 8KB)

typedef __attribute__((ext_vector_type(4)))  float f32x4;
typedef __attribute__((ext_vector_type(16))) float f32x16;
typedef __attribute__((ext_vector_type(4)))  int   i32x4;
typedef __attribute__((ext_vector_type(8)))  int   i32x8;

#define GLDS(gptr, lptr)                                                       \
    __builtin_amdgcn_global_load_lds(                                          \
        (const __attribute__((address_space(1))) void*)(gptr),                 \
        (__attribute__((address_space(3))) void*)(lptr), 16, 0, 0)

#define SCHED0() __builtin_amdgcn_sched_barrier(0)
#define BARRIER() __builtin_amdgcn_s_barrier()
#define LGKMC(n) do { asm volatile("s_waitcnt lgkmcnt(" #n ")" ::: "memory"); SCHED0(); } while (0)
#define VMCNT(n)  do { asm volatile("s_waitcnt vmcnt(" #n ")" ::: "memory"); SCHED0(); } while (0)
#define PRIO1() __builtin_amdgcn_s_setprio(1)
#define PRIO0() __builtin_amdgcn_s_setprio(0)

#define SCALE1 0x7F7F7F7F   // E8M0 = 1.0 in every byte

// fp4 data occupies the low 4 regs of the 8-reg operand
#define EXT8(x) __builtin_shufflevector((x), (i32x4){0, 0, 0, 0}, 0, 1, 2, 3, 4, 5, 6, 7)
// FMT code 4 = fp4 (e2m1) for both A (cbsz) and B (blgp)
#define MFMA32(a, b, c)                                                        \
    __builtin_amdgcn_mfma_scale_f32_32x32x64_f8f6f4(                           \
        EXT8(a), EXT8(b), (c), 4, 4, 0, SCALE1, 0, SCALE1)

// ---- COO scatter with duplicate summing ----
__global__ void build_w_kernel(const float* __restrict__ vals,
                               const int* __restrict__ rows,
                               const int* __restrict__ cols,
                               float* __restrict__ W, int nnz) {
    int k = blockIdx.x * blockDim.x + threadIdx.x;
    if (k < nnz) atomicAdd(&W[(size_t)rows[k] * HIDDEN + cols[k]], vals[k]);
}

// ---- e2m1 quantize (RNE by midpoint thresholds) ----
__device__ __forceinline__ unsigned q_e2m1(float x) {
    float v = fabsf(x);
    unsigned n;
    if      (v < 0.25f) n = 0;
    else if (v < 0.75f) n = 1;   // 0.5
    else if (v < 1.25f) n = 2;   // 1.0
    else if (v < 1.75f) n = 3;   // 1.5
    else if (v < 2.5f)  n = 4;   // 2
    else if (v < 3.5f)  n = 5;   // 3
    else if (v < 5.0f)  n = 6;   // 4
    else                n = 7;   // 6
    return n | (x < 0.0f ? 8u : 0u);
}

__device__ __forceinline__ unsigned pack8_e2m1(const f32x4& a, const f32x4& b,
                                               float scale) {
    unsigned w = 0;
    #pragma unroll
    for (int k = 0; k < 4; ++k) {
        w |= q_e2m1(a[k] * scale) << (4 * k);
        w |= q_e2m1(b[k] * scale) << (16 + 4 * k);
    }
    return w;
}

// ---- fused: zero W (f32) + convert xp -> fp4 (independent streams) ----
__global__ void prep_kernel(float* __restrict__ W, int nW4,
                            const float* __restrict__ xp,
                            unsigned int* __restrict__ xp4, int n8xp) {
    const int stride = gridDim.x * blockDim.x;
    const int i = blockIdx.x * blockDim.x + threadIdx.x;
    for (int j = i; j < nW4; j += stride)
        ((f32x4*)W)[j] = (f32x4){0.f, 0.f, 0.f, 0.f};
    for (int j = i; j < n8xp; j += stride) {
        f32x4 a = ((const f32x4*)xp)[2 * j];
        f32x4 b = ((const f32x4*)xp)[2 * j + 1];
        xp4[j] = pack8_e2m1(a, b, 1.0f);
    }
}

// ---- convert W (f32, x1024) -> fp4 ----
__global__ void convw_kernel(const float* __restrict__ W,
                             unsigned int* __restrict__ W4, int n8) {
    const int stride = gridDim.x * blockDim.x;
    for (int j = blockIdx.x * blockDim.x + threadIdx.x; j < n8; j += stride) {
        f32x4 a = ((const f32x4*)W)[2 * j];
        f32x4 b = ((const f32x4*)W)[2 * j + 1];
        W4[j] = pack8_e2m1(a, b, 1024.0f);
    }
}

// ---- 256x128xK128 8-wave MX-fp4 GEMM, 32x32x64 MFMA, 2 blocks/CU ----
__global__ __launch_bounds__(512, 4) void gemm_kernel(
    const float* __restrict__ xc,
    const unsigned char* __restrict__ xp4,   // fp4 [8192][1024 B]
    const unsigned char* __restrict__ w4,    // fp4 [2048][1024 B], values x1024
    const float* __restrict__ alpha_p,
    float* __restrict__ out)
{
    extern __shared__ __align__(16) char lds[];

    const int tid  = threadIdx.x;
    const int lane = tid & 63;
    const int wave = tid >> 6;
    const int l31  = lane & 31;
    const int kh   = lane >> 5;         // k-half within MFMA operand

    // XCD-chunked bijective mapping: 512 blocks = 8 XCD x (4 m-tiles x 16 n-tiles)
    const int xcd = blockIdx.x & 7;
    const int loc = blockIdx.x >> 3;          // 0..63
    const int m0  = (xcd * 4 + (loc >> 4)) * 256;
    const int n0  = (loc & 15) * 128;

    const int wm = (wave >> 1) * 64;    // 4 M-waves
    const int wn = (wave & 1) * 64;     // 2 N-waves

    // ---- staging: A tile 256r x 64B (2 GLDS/thread), B tile 128r (1 GLDS) ----
    // lane covers local row lr = lane>>2 (0..15) per 16-row group, slot = lane&3.
    // Source-swizzle by row%32: swz(r) = ((r>>1)&3) ^ ((r>>3)&3).
    const int lr = lane >> 2;
    const int rA0 = lr;                       // A g=0: row%32 = lr
    const int rA1 = lr + 16;                  // A g=1: row%32 = lr+16
    const int rB  = ((wave & 1) * 16) + lr;   // B: row%32
    const int swA0 = (lane & 3) ^ ((rA0 >> 1) & 3) ^ ((rA0 >> 3) & 3);
    const int swA1 = (lane & 3) ^ ((rA1 >> 1) & 3) ^ ((rA1 >> 3) & 3);
    const int swB  = (lane & 3) ^ ((rB  >> 1) & 3) ^ ((rB  >> 3) & 3);

    const unsigned char* const gA0 = xp4 + (size_t)(m0 + wave * 32 + lr)      * 1024 + swA0 * 16;
    const unsigned char* const gA1 = xp4 + (size_t)(m0 + wave * 32 + 16 + lr) * 1024 + swA1 * 16;
    const unsigned char* const gB  = w4  + (size_t)(n0 + wave * 16 + lr)      * 1024 + swB  * 16;

#define STAGE(t)                                                               \
    do {                                                                       \
        const int _t = (t);                                                    \
        if (_t < NT) {                                                         \
            const size_t _o = (size_t)_t * 64;                                 \
            char* const _dA = lds + (_t & 1) * 24576 + wave * 2048 + lane * 16;\
            char* const _dB = lds + (_t & 1) * 24576 + 16384 + wave * 1024 + lane * 16; \
            GLDS(gA0 + _o, _dA);                                               \
            GLDS(gA1 + _o, _dA + 1024);                                       \
            GLDS(gB  + _o, _dB);                                               \
        }                                                                      \
    } while (0)

    // ---- ds_read: lane reads row (base + l31); chunk (kk*2 + kh) ^ swz(l31) ----
    const int swzr = ((l31 >> 1) & 3) ^ ((l31 >> 3) & 3);
    const int kx0  = ((0 + kh) ^ swzr) * 16;   // kk = 0
    const int kx1  = ((2 + kh) ^ swzr) * 16;   // kk = 1
    const int rowb = l31 * 64;

    f32x16 acc[2][2] = {};      // [mi][nj] 32x32 fragments
    i32x4 a0[2], a1[2], b0[2], b1[2];   // [mi]/[nj], kk=0 and kk=1 sets

    // ---- prologue ----
    STAGE(0);
    VMCNT(0);
    SCHED0(); BARRIER(); SCHED0();

    for (int tt = 0; tt < NT; ++tt) {
        const char* const Ab = lds + (tt & 1) * 24576 + wm * 64;
        const char* const Bb = lds + (tt & 1) * 24576 + 16384 + wn * 64;

        STAGE(tt + 1);           // 3 vm loads; waited at the bottom VMCNT
        SCHED0();

        // -- issue kk=0 reads (4) then kk=1 reads (4) --
        #pragma unroll
        for (int mi = 0; mi < 2; ++mi)
            a0[mi] = *(const i32x4*)(Ab + mi * 2048 + rowb + kx0);
        #pragma unroll
        for (int nj = 0; nj < 2; ++nj)
            b0[nj] = *(const i32x4*)(Bb + nj * 2048 + rowb + kx0);
        SCHED0();
        #pragma unroll
        for (int mi = 0; mi < 2; ++mi)
            a1[mi] = *(const i32x4*)(Ab + mi * 2048 + rowb + kx1);
        #pragma unroll
        for (int nj = 0; nj < 2; ++nj)
            b1[nj] = *(const i32x4*)(Bb + nj * 2048 + rowb + kx1);
        SCHED0();
        LGKMC(4);                // kk=0 operands ready (kk=1 flying)

        PRIO1();                 // 4 MFMAs, kk=0
        #pragma unroll
        for (int mi = 0; mi < 2; ++mi)
            #pragma unroll
            for (int nj = 0; nj < 2; ++nj)
                acc[mi][nj] = MFMA32(a0[mi], b0[nj], acc[mi][nj]);
        PRIO0();
        SCHED0();
        LGKMC(0);                // kk=1 operands ready

        PRIO1();                 // 4 MFMAs, kk=1
        #pragma unroll
        for (int mi = 0; mi < 2; ++mi)
            #pragma unroll
            for (int nj = 0; nj < 2; ++nj)
                acc[mi][nj] = MFMA32(a1[mi], b1[nj], acc[mi][nj]);
        PRIO0();
        SCHED0();

        VMCNT(0);                // tile t+1 landed (issued a full body ago)
        BARRIER(); SCHED0();
    }

    // ---- epilogue: out = xc + (alpha/1024) * acc ----
    // 32x32 C/D map (m74/m101): col = lane&31, row = (r&3) + 8*(r>>2) + 4*(lane>>5)
    const float alpha = alpha_p[0] * (1.0f / 1024.0f);
    #pragma unroll
    for (int mi = 0; mi < 2; ++mi) {
        #pragma unroll
        for (int r = 0; r < 16; ++r) {
            const int m = m0 + wm + mi * 32 + (r & 3) + 8 * (r >> 2) + 4 * kh;
            #pragma unroll
            for (int nj = 0; nj < 2; ++nj) {
                const int n = n0 + wn + nj * 32 + l31;
                const size_t o = (size_t)m * HIDDEN + n;
                __builtin_nontemporal_store(xc[o] + alpha * acc[mi][nj][r], &out[o]);
            }
        }
    }
#undef STAGE
}

extern "C" void kernel_launch(void* const* d_in, const int* in_sizes, int n_in,
                              void* d_out, int out_size, void* d_ws, size_t ws_size,
                              hipStream_t stream) {
    const float* xc    = (const float*)d_in[0];
    const float* xp    = (const float*)d_in[1];
    const float* alpha = (const float*)d_in[2];
    const float* vals  = (const float*)d_in[3];
    const int*   idx   = (const int*)d_in[4];
    float* out = (float*)d_out;

    float*         W   = (float*)d_ws;                                  // 16 MB
    unsigned char* W4  = (unsigned char*)((char*)d_ws + (16 << 20));    //  2 MB
    unsigned char* xp4 = (unsigned char*)((char*)d_ws + (18 << 20));    // 8.4 MB

    const int nnz = in_sizes[3];
    const int M   = in_sizes[0] / HIDDEN;   // 8192

    (void)hipFuncSetAttribute((const void*)gemm_kernel,
                              hipFuncAttributeMaxDynamicSharedMemorySize, LDS_BYTES);

    // 1) zero W + convert xp (fused, independent)  2) scatter  3) convert W
    prep_kernel<<<2048, 256, 0, stream>>>(W, (HIDDEN * HIDDEN) / 4,
                                          xp, (unsigned int*)xp4, in_sizes[1] / 8);
    build_w_kernel<<<(nnz + 255) / 256, 256, 0, stream>>>(vals, idx, idx + nnz, W, nnz);
    convw_kernel<<<1024, 256, 0, stream>>>(W, (unsigned int*)W4, (HIDDEN * HIDDEN) / 8);

    dim3 grid((M / 256) * 16);   // 32 m-tiles x 16 n-tiles = 512 blocks (2/CU)
    gemm_kernel<<<grid, 512, LDS_BYTES, stream>>>(xc, xp4, W4, alpha, out);
}